// Round 1
// baseline (281.978 us; speedup 1.0000x reference)
//
#include <hip/hip_runtime.h>

#define DEV __device__ __forceinline__

typedef __attribute__((ext_vector_type(8))) short bf16x8;
typedef __attribute__((ext_vector_type(4))) float f32x4;

DEV float b2f(unsigned short u) {
    unsigned int v = ((unsigned int)u) << 16;
    float f; __builtin_memcpy(&f, &v, 4); return f;
}
DEV unsigned short f2b(float f) {
    unsigned int v; __builtin_memcpy(&v, &f, 4);
    v = (v + 0x7fffu + ((v >> 16) & 1u)) >> 16;
    return (unsigned short)v;
}

DEV f32x4 mfma16(bf16x8 a, bf16x8 b, f32x4 c) {
    return __builtin_amdgcn_mfma_f32_16x16x32_bf16(a, b, c, 0, 0, 0);
}

constexpr float SCALE = 0.125f;           // DH^-0.5, DH=64
constexpr float L2E   = 1.44269504088896340736f;

// ---------------------------------------------------------------------------
// K0: fp32 -> bf16 conversions.
//  xb[4096][512]    = x
//  wt[1664][512]    = [wq_s | wk_s | wv_r | wq_r]^T   (B^T form for MFMA)
//  wot[512][512]    = w_out^T
// ---------------------------------------------------------------------------
__global__ void k_convert(const float* __restrict__ x,
                          const float* __restrict__ wq_s, const float* __restrict__ wk_s,
                          const float* __restrict__ wv_r, const float* __restrict__ wq_r,
                          const float* __restrict__ w_out,
                          unsigned short* __restrict__ xb,
                          unsigned short* __restrict__ wt,
                          unsigned short* __restrict__ wot)
{
    const int T1 = 4096 * 512;
    const int T2 = 1664 * 512;
    const int T3 = 512 * 512;
    const int total = T1 + T2 + T3;
    for (int idx = blockIdx.x * blockDim.x + threadIdx.x; idx < total;
         idx += gridDim.x * blockDim.x) {
        if (idx < T1) {
            xb[idx] = f2b(x[idx]);
        } else if (idx < T1 + T2) {
            int t = idx - T1;
            int n = t >> 9, k = t & 511;   // t == n*512 + k
            float v;
            if (n < 512)       v = wq_s[k * 512 + n];
            else if (n < 1024) v = wk_s[k * 512 + (n - 512)];
            else if (n < 1152) v = wv_r[k * 128 + (n - 1024)];
            else               v = wq_r[k * 512 + (n - 1152)];
            wt[t] = f2b(v);
        } else {
            int t = idx - T1 - T2;
            int n = t >> 9, k = t & 511;
            wot[t] = f2b(w_out[k * 512 + n]);
        }
    }
}

// ---------------------------------------------------------------------------
// K1: projection GEMM  C[4096][1664] = xb @ wt^T, epilogue scatters into
//     qs/ks/rqb  (bf16[b][s][n][64], q's pre-scaled) and vt (bf16[b][128][n]).
// grid (64, 26), 256 threads (4 waves x 16 rows, 64 cols/block)
// ---------------------------------------------------------------------------
__global__ __launch_bounds__(256) void k_proj(const unsigned short* __restrict__ xb,
                                              const unsigned short* __restrict__ wt,
                                              unsigned short* __restrict__ qs,
                                              unsigned short* __restrict__ ks,
                                              unsigned short* __restrict__ rqb,
                                              unsigned short* __restrict__ vt)
{
    const int lane = threadIdx.x & 63, wid = threadIdx.x >> 6;
    const int lr = lane & 15, lg = lane >> 4;
    const int row0 = blockIdx.x * 64 + wid * 16;
    const int col0 = blockIdx.y * 64;

    const f32x4 z = {0.f, 0.f, 0.f, 0.f};
    f32x4 acc[4];
#pragma unroll
    for (int ct = 0; ct < 4; ++ct) acc[ct] = z;

    const unsigned short* ap = xb + (row0 + lr) * 512 + lg * 8;
#pragma unroll 4
    for (int k0 = 0; k0 < 512; k0 += 32) {
        bf16x8 a = *(const bf16x8*)(ap + k0);
#pragma unroll
        for (int ct = 0; ct < 4; ++ct) {
            bf16x8 b = *(const bf16x8*)(wt + (col0 + ct * 16 + lr) * 512 + k0 + lg * 8);
            acc[ct] = mfma16(a, b, acc[ct]);
        }
    }

#pragma unroll
    for (int ct = 0; ct < 4; ++ct) {
#pragma unroll
        for (int i = 0; i < 4; ++i) {
            int gr = row0 + lg * 4 + i;          // 0..4095
            int gc = col0 + ct * 16 + lr;        // 0..1663
            float v = acc[ct][i];
            int b = gr >> 11, in = gr & 2047;
            if (gc < 512) {
                int s = gc >> 6, d = gc & 63;
                qs[((b * 8 + s) * 2048 + in) * 64 + d] = f2b(v * SCALE);
            } else if (gc < 1024) {
                int c = gc - 512; int s = c >> 6, d = c & 63;
                ks[((b * 8 + s) * 2048 + in) * 64 + d] = f2b(v);
            } else if (gc < 1152) {
                int c = gc - 1024;               // 0..127 = r*64+d
                vt[(b * 128 + c) * 2048 + in] = f2b(v);
            } else {
                int c = gc - 1152; int s = c >> 6, d = c & 63;
                rqb[((b * 8 + s) * 2048 + in) * 64 + d] = f2b(v * SCALE);
            }
        }
    }
}

// ---------------------------------------------------------------------------
// K2: flash attention (stage 1) + fused retrieval composition (stage 2).
// grid 512 = (b*s)[16] x qtile[32]; 256 threads = 4 waves x 16 query rows.
// Per (b,s): Q,K (2048x64), V = vt (128 x 2048, transposed). Online softmax
// over K-tiles of 32. Epilogue: rk = retrieved@wk_ret, softmax over r=2,
// combine -> ob[b][n][s*64+d] bf16.
// ---------------------------------------------------------------------------
__global__ __launch_bounds__(256) void k_attn(const unsigned short* __restrict__ qs,
                                              const unsigned short* __restrict__ ks,
                                              const unsigned short* __restrict__ rqb,
                                              const unsigned short* __restrict__ vt,
                                              const float* __restrict__ wk_ret,
                                              unsigned short* __restrict__ ob)
{
    __shared__ float wk_lds[64 * 64];                 // 16 KB
    __shared__ unsigned short p_lds[4][16][40];       // 5 KB  (pad 32->40: 2-way = free)
    __shared__ float retr_lds[4][16][132];            // 33 KB (pad 128->132)

    const int tid = threadIdx.x;
    for (int i = tid; i < 4096; i += 256) wk_lds[i] = wk_ret[i];
    __syncthreads();

    const int lane = tid & 63, wid = tid >> 6;
    const int lr = lane & 15, lg = lane >> 4;
    const int bid = blockIdx.x;
    const int bs = bid >> 5, qt = bid & 31;           // bs = b*8+s
    const int gb = bs >> 3, gs = bs & 7;
    const int qrow0 = qt * 64 + wid * 16;

    // Q fragments, kept in registers for the whole kernel
    const unsigned short* qbase = qs + ((size_t)bs * 2048 + qrow0 + lr) * 64 + lg * 8;
    const bf16x8 q0 = *(const bf16x8*)(qbase);
    const bf16x8 q1 = *(const bf16x8*)(qbase + 32);

    const unsigned short* kbase = ks + (size_t)bs * 2048 * 64;
    const unsigned short* vbase = vt + (size_t)gb * 128 * 2048;

    const f32x4 z = {0.f, 0.f, 0.f, 0.f};
    float m_r[4], l_r[4];
    f32x4 acc[8];
#pragma unroll
    for (int i = 0; i < 4; ++i) { m_r[i] = -3.0e38f; l_r[i] = 0.f; }
#pragma unroll
    for (int c8 = 0; c8 < 8; ++c8) acc[c8] = z;

    for (int kt = 0; kt < 64; ++kt) {
        const int k0 = kt * 32;
        // --- S = Q K^T (16 x 32 tile), 2 col-tiles of 16
        f32x4 s[2];
#pragma unroll
        for (int ct = 0; ct < 2; ++ct) {
            const unsigned short* kp = kbase + (k0 + ct * 16 + lr) * 64 + lg * 8;
            bf16x8 kf0 = *(const bf16x8*)(kp);
            bf16x8 kf1 = *(const bf16x8*)(kp + 32);
            f32x4 t = z;
            t = mfma16(q0, kf0, t);
            t = mfma16(q1, kf1, t);
            s[ct] = t;
        }
        // --- online softmax; lane holds rows lg*4+i, cols lr / 16+lr
#pragma unroll
        for (int i = 0; i < 4; ++i) {
            float mx = fmaxf(s[0][i], s[1][i]);
            mx = fmaxf(mx, __shfl_xor(mx, 1, 16));
            mx = fmaxf(mx, __shfl_xor(mx, 2, 16));
            mx = fmaxf(mx, __shfl_xor(mx, 4, 16));
            mx = fmaxf(mx, __shfl_xor(mx, 8, 16));
            float m_new = fmaxf(m_r[i], mx);
            float alpha = exp2f((m_r[i] - m_new) * L2E);
            float p0 = exp2f((s[0][i] - m_new) * L2E);
            float p1 = exp2f((s[1][i] - m_new) * L2E);
            float rs = p0 + p1;
            rs += __shfl_xor(rs, 1, 16);
            rs += __shfl_xor(rs, 2, 16);
            rs += __shfl_xor(rs, 4, 16);
            rs += __shfl_xor(rs, 8, 16);
            l_r[i] = l_r[i] * alpha + rs;
            m_r[i] = m_new;
#pragma unroll
            for (int c8 = 0; c8 < 8; ++c8) acc[c8][i] *= alpha;
            p_lds[wid][lg * 4 + i][lr]      = f2b(p0);
            p_lds[wid][lg * 4 + i][16 + lr] = f2b(p1);
        }
        // --- P (A-frag from LDS) x V^T (B-frags direct from global)
        bf16x8 pf = *(const bf16x8*)(&p_lds[wid][lr][lg * 8]);
#pragma unroll
        for (int c8 = 0; c8 < 8; ++c8) {
            bf16x8 vf = *(const bf16x8*)(vbase + (size_t)(c8 * 16 + lr) * 2048 + k0 + lg * 8);
            acc[c8] = mfma16(pf, vf, acc[c8]);
        }
    }

    // --- normalize; retrieved -> LDS (fp32), rows=query, cols 0..127 = r*64+d
    float inv[4];
#pragma unroll
    for (int i = 0; i < 4; ++i) inv[i] = 1.0f / l_r[i];
#pragma unroll
    for (int c8 = 0; c8 < 8; ++c8)
#pragma unroll
        for (int i = 0; i < 4; ++i)
            retr_lds[wid][lg * 4 + i][c8 * 16 + lr] = acc[c8][i] * inv[i];

    // --- stage 2: lane handles row = lr, d'-quarter qq = lg
    // t[d'] = sum_d wk_ret[d'][d] * rq[row][d];  sim_r = sum_d' retr[r][d']*t[d']
    const int row = lr, qq = lg;
    float t[16];
#pragma unroll
    for (int dp = 0; dp < 16; ++dp) t[dp] = 0.f;
    const unsigned short* rqrow = rqb + ((size_t)bs * 2048 + qrow0 + row) * 64;
#pragma unroll
    for (int dc = 0; dc < 8; ++dc) {
        bf16x8 rc = *(const bf16x8*)(rqrow + dc * 8);
        float rf[8];
#pragma unroll
        for (int j = 0; j < 8; ++j) rf[j] = b2f((unsigned short)rc[j]);
#pragma unroll
        for (int dp = 0; dp < 16; ++dp) {
            float acc_t = t[dp];
#pragma unroll
            for (int j = 0; j < 8; ++j)
                acc_t += wk_lds[(qq * 16 + dp) * 64 + dc * 8 + j] * rf[j];
            t[dp] = acc_t;
        }
    }
    float sim0 = 0.f, sim1 = 0.f;
#pragma unroll
    for (int dp = 0; dp < 16; ++dp) {
        sim0 += t[dp] * retr_lds[wid][row][qq * 16 + dp];
        sim1 += t[dp] * retr_lds[wid][row][64 + qq * 16 + dp];
    }
    sim0 += __shfl_xor(sim0, 16, 64); sim0 += __shfl_xor(sim0, 32, 64);
    sim1 += __shfl_xor(sim1, 16, 64); sim1 += __shfl_xor(sim1, 32, 64);
    float mm = fmaxf(sim0, sim1);
    float w0 = exp2f((sim0 - mm) * L2E);
    float w1 = exp2f((sim1 - mm) * L2E);
    float wsum = w0 + w1; w0 /= wsum; w1 /= wsum;

    // --- combine and write ob[b][n][gs*64 + d], 16 d per lane
    bf16x8 o0, o1;
#pragma unroll
    for (int j = 0; j < 8; ++j) {
        int d = qq * 16 + j;
        o0[j] = (short)f2b(w0 * retr_lds[wid][row][d] + w1 * retr_lds[wid][row][64 + d]);
        o1[j] = (short)f2b(w0 * retr_lds[wid][row][d + 8] + w1 * retr_lds[wid][row][64 + d + 8]);
    }
    unsigned short* op = ob + ((size_t)gb * 2048 + qrow0 + row) * 512 + gs * 64 + qq * 16;
    *(bf16x8*)(op) = o0;
    *(bf16x8*)(op + 8) = o1;
}

// ---------------------------------------------------------------------------
// K3: final GEMM  out[4096][512] (fp32) = ob(bf16) @ w_out, via wot = w_out^T
// grid (64, 8), 256 threads
// ---------------------------------------------------------------------------
__global__ __launch_bounds__(256) void k_out(const unsigned short* __restrict__ ob,
                                             const unsigned short* __restrict__ wot,
                                             float* __restrict__ out)
{
    const int lane = threadIdx.x & 63, wid = threadIdx.x >> 6;
    const int lr = lane & 15, lg = lane >> 4;
    const int row0 = blockIdx.x * 64 + wid * 16;
    const int col0 = blockIdx.y * 64;

    const f32x4 z = {0.f, 0.f, 0.f, 0.f};
    f32x4 acc[4];
#pragma unroll
    for (int ct = 0; ct < 4; ++ct) acc[ct] = z;

    const unsigned short* ap = ob + (row0 + lr) * 512 + lg * 8;
#pragma unroll 4
    for (int k0 = 0; k0 < 512; k0 += 32) {
        bf16x8 a = *(const bf16x8*)(ap + k0);
#pragma unroll
        for (int ct = 0; ct < 4; ++ct) {
            bf16x8 b = *(const bf16x8*)(wot + (col0 + ct * 16 + lr) * 512 + k0 + lg * 8);
            acc[ct] = mfma16(a, b, acc[ct]);
        }
    }
#pragma unroll
    for (int ct = 0; ct < 4; ++ct)
#pragma unroll
        for (int i = 0; i < 4; ++i)
            out[(size_t)(row0 + lg * 4 + i) * 512 + col0 + ct * 16 + lr] = acc[ct][i];
}

// ---------------------------------------------------------------------------
extern "C" void kernel_launch(void* const* d_in, const int* in_sizes, int n_in,
                              void* d_out, int out_size, void* d_ws, size_t ws_size,
                              hipStream_t stream)
{
    (void)in_sizes; (void)n_in; (void)out_size; (void)ws_size;
    const float* x      = (const float*)d_in[0];
    const float* wq_s   = (const float*)d_in[1];
    const float* wk_s   = (const float*)d_in[2];
    const float* wv_r   = (const float*)d_in[3];
    const float* wq_r   = (const float*)d_in[4];
    const float* wk_ret = (const float*)d_in[5];
    const float* w_out  = (const float*)d_in[6];

    char* ws = (char*)d_ws;                            // needs ~24.3 MB
    unsigned short* xb  = (unsigned short*)(ws + 0);          // [4096][512]
    unsigned short* wt  = (unsigned short*)(ws + 4194304);    // [1664][512]
    unsigned short* qsb = (unsigned short*)(ws + 5898240);    // [2][8][2048][64]
    unsigned short* ksb = (unsigned short*)(ws + 10092544);   // [2][8][2048][64]
    unsigned short* rqb = (unsigned short*)(ws + 14286848);   // [2][8][2048][64]
    unsigned short* vtb = (unsigned short*)(ws + 18481152);   // [2][128][2048]
    unsigned short* obb = (unsigned short*)(ws + 19529728);   // [2][2048][512]
    unsigned short* wot = (unsigned short*)(ws + 23724032);   // [512][512]

    hipLaunchKernelGGL(k_convert, dim3(2048), dim3(256), 0, stream,
                       x, wq_s, wk_s, wv_r, wq_r, w_out, xb, wt, wot);
    hipLaunchKernelGGL(k_proj, dim3(64, 26), dim3(256), 0, stream,
                       xb, wt, qsb, ksb, rqb, vtb);
    hipLaunchKernelGGL(k_attn, dim3(512), dim3(256), 0, stream,
                       qsb, ksb, rqb, vtb, wk_ret, obb);
    hipLaunchKernelGGL(k_out, dim3(64, 8), dim3(256), 0, stream,
                       obb, wot, (float*)d_out);
}

// Round 2
// 279.340 us; speedup vs baseline: 1.0094x; 1.0094x over previous
//
#include <hip/hip_runtime.h>
#include <hip/hip_bf16.h>

#define DEV __device__ __forceinline__

typedef __attribute__((ext_vector_type(8))) short bf16x8;
typedef __attribute__((ext_vector_type(4))) float f32x4;

DEV float b2f(unsigned short u) {
    unsigned int v = ((unsigned int)u) << 16;
    float f; __builtin_memcpy(&f, &v, 4); return f;
}
DEV unsigned short f2b(float f) {            // RNE via bit-ops (host-independent)
    unsigned int v; __builtin_memcpy(&v, &f, 4);
    v = (v + 0x7fffu + ((v >> 16) & 1u)) >> 16;
    return (unsigned short)v;
}
DEV unsigned short f2b_hw(float f) {         // hardware cvt (RNE), 1-2 VALU ops
    __hip_bfloat16 h = __float2bfloat16(f);
    unsigned short u; __builtin_memcpy(&u, &h, 2); return u;
}

DEV f32x4 mfma16(bf16x8 a, bf16x8 b, f32x4 c) {
    return __builtin_amdgcn_mfma_f32_16x16x32_bf16(a, b, c, 0, 0, 0);
}

constexpr float SCALE_L2E = 0.125f * 1.44269504088896340736f;  // DH^-0.5 * log2(e)

// ---------------------------------------------------------------------------
// K0: fp32 -> bf16 conversions.
//  xb[4096][512]    = x
//  wt[1664][512]    = [wq_s | wk_s | wv_r | wq_r]^T   (B^T form for MFMA)
//  wot[512][512]    = w_out^T
// ---------------------------------------------------------------------------
__global__ void k_convert(const float* __restrict__ x,
                          const float* __restrict__ wq_s, const float* __restrict__ wk_s,
                          const float* __restrict__ wv_r, const float* __restrict__ wq_r,
                          const float* __restrict__ w_out,
                          unsigned short* __restrict__ xb,
                          unsigned short* __restrict__ wt,
                          unsigned short* __restrict__ wot)
{
    const int T1 = 4096 * 512;
    const int T2 = 1664 * 512;
    const int T3 = 512 * 512;
    const int total = T1 + T2 + T3;
    for (int idx = blockIdx.x * blockDim.x + threadIdx.x; idx < total;
         idx += gridDim.x * blockDim.x) {
        if (idx < T1) {
            xb[idx] = f2b(x[idx]);
        } else if (idx < T1 + T2) {
            int t = idx - T1;
            int n = t >> 9, k = t & 511;   // t == n*512 + k
            float v;
            if (n < 512)       v = wq_s[k * 512 + n];
            else if (n < 1024) v = wk_s[k * 512 + (n - 512)];
            else if (n < 1152) v = wv_r[k * 128 + (n - 1024)];
            else               v = wq_r[k * 512 + (n - 1152)];
            wt[t] = f2b(v);
        } else {
            int t = idx - T1 - T2;
            int n = t >> 9, k = t & 511;
            wot[t] = f2b(w_out[k * 512 + n]);
        }
    }
}

// ---------------------------------------------------------------------------
// K1: projection GEMM  C[4096][1664] = xb @ wt^T, epilogue scatters into
//     qs/ks/rqb  (bf16[b][s][n][64], q's pre-scaled by DH^-0.5 * log2e)
//     and vt (bf16[b][128][n], transposed V).
// grid (64, 26), 256 threads (4 waves x 16 rows, 64 cols/block)
// ---------------------------------------------------------------------------
__global__ __launch_bounds__(256) void k_proj(const unsigned short* __restrict__ xb,
                                              const unsigned short* __restrict__ wt,
                                              unsigned short* __restrict__ qs,
                                              unsigned short* __restrict__ ks,
                                              unsigned short* __restrict__ rqb,
                                              unsigned short* __restrict__ vt)
{
    const int lane = threadIdx.x & 63, wid = threadIdx.x >> 6;
    const int lr = lane & 15, lg = lane >> 4;
    const int row0 = blockIdx.x * 64 + wid * 16;
    const int col0 = blockIdx.y * 64;

    const f32x4 z = {0.f, 0.f, 0.f, 0.f};
    f32x4 acc[4];
#pragma unroll
    for (int ct = 0; ct < 4; ++ct) acc[ct] = z;

    const unsigned short* ap = xb + (row0 + lr) * 512 + lg * 8;
#pragma unroll 4
    for (int k0 = 0; k0 < 512; k0 += 32) {
        bf16x8 a = *(const bf16x8*)(ap + k0);
#pragma unroll
        for (int ct = 0; ct < 4; ++ct) {
            bf16x8 b = *(const bf16x8*)(wt + (col0 + ct * 16 + lr) * 512 + k0 + lg * 8);
            acc[ct] = mfma16(a, b, acc[ct]);
        }
    }

#pragma unroll
    for (int ct = 0; ct < 4; ++ct) {
#pragma unroll
        for (int i = 0; i < 4; ++i) {
            int gr = row0 + lg * 4 + i;          // 0..4095
            int gc = col0 + ct * 16 + lr;        // 0..1663
            float v = acc[ct][i];
            int b = gr >> 11, in = gr & 2047;
            if (gc < 512) {
                int s = gc >> 6, d = gc & 63;
                qs[((b * 8 + s) * 2048 + in) * 64 + d] = f2b(v * SCALE_L2E);
            } else if (gc < 1024) {
                int c = gc - 512; int s = c >> 6, d = c & 63;
                ks[((b * 8 + s) * 2048 + in) * 64 + d] = f2b(v);
            } else if (gc < 1152) {
                int c = gc - 1024;               // 0..127 = r*64+d
                vt[(b * 128 + c) * 2048 + in] = f2b(v);
            } else {
                int c = gc - 1152; int s = c >> 6, d = c & 63;
                rqb[((b * 8 + s) * 2048 + in) * 64 + d] = f2b(v * SCALE_L2E);
            }
        }
    }
}

// ---------------------------------------------------------------------------
// K2: flash attention (stage 1) + fused retrieval composition (stage 2).
// grid 512 = (b*s)[16] x qtile[32]; 256 threads = 4 waves x 16 query rows.
// KVBLK=64. Everything in exp2 (log2) units: Q pre-scaled by DH^-0.5*log2e.
//  - defer-max (THR=8): fast path = lane-local max test + __any vote only;
//    full shuffle-reduce + acc rescale only when the max actually grows.
//  - row-sum l via MFMA ones-trick: acc_l = mfma(pf, ones, acc_l).
//  - V frags issued at tile top (latency under QK^T+softmax), K frags for
//    tile t+1 prefetched right after QK^T.
// Epilogue: rk = retrieved@wk_ret, softmax over r=2, combine -> ob bf16.
// ---------------------------------------------------------------------------
__global__ __launch_bounds__(256, 2) void k_attn(const unsigned short* __restrict__ qs,
                                                 const unsigned short* __restrict__ ks,
                                                 const unsigned short* __restrict__ rqb,
                                                 const unsigned short* __restrict__ vt,
                                                 const float* __restrict__ wk_ret,
                                                 unsigned short* __restrict__ ob)
{
    __shared__ float wk_lds[64 * 64];                 // 16 KB
    __shared__ unsigned short p_lds[4][16][72];       // 9 KB (pad 64->72)
    __shared__ float retr_lds[4][16][132];            // 33 KB (pad 128->132)

    const int tid = threadIdx.x;
    for (int i = tid; i < 4096; i += 256) wk_lds[i] = wk_ret[i];
    __syncthreads();

    const int lane = tid & 63, wid = tid >> 6;
    const int lr = lane & 15, lg = lane >> 4;
    const int bid = blockIdx.x;
    const int bs = bid >> 5, qt = bid & 31;           // bs = b*8+s
    const int gb = bs >> 3, gs = bs & 7;
    const int qrow0 = qt * 64 + wid * 16;

    // Q fragments, kept in registers for the whole kernel
    const unsigned short* qbase = qs + ((size_t)bs * 2048 + qrow0 + lr) * 64 + lg * 8;
    const bf16x8 q0 = *(const bf16x8*)(qbase);
    const bf16x8 q1 = *(const bf16x8*)(qbase + 32);

    const unsigned short* kpl = ks + (size_t)bs * 2048 * 64 + lr * 64 + lg * 8;
    const unsigned short* vpl = vt + (size_t)gb * 128 * 2048 + lr * 2048 + lg * 8;

    const f32x4 z = {0.f, 0.f, 0.f, 0.f};
    bf16x8 ones;
#pragma unroll
    for (int j = 0; j < 8; ++j) ones[j] = (short)0x3F80;

    float m_r[4];
    f32x4 acc[8];
    f32x4 acc_l = z;
#pragma unroll
    for (int i = 0; i < 4; ++i) m_r[i] = -3.0e38f;
#pragma unroll
    for (int c8 = 0; c8 < 8; ++c8) acc[c8] = z;

    // preload K frags for tile 0: kf[ct*2+ks] = K^T frag, rows ct*16+lr
    bf16x8 kf[8];
#pragma unroll
    for (int ct = 0; ct < 4; ++ct)
#pragma unroll
        for (int ksb = 0; ksb < 2; ++ksb)
            kf[ct * 2 + ksb] = *(const bf16x8*)(kpl + ct * 1024 + ksb * 32);

    for (int kt = 0; kt < 32; ++kt) {
        const int k0 = kt * 64;
        // --- issue V loads for this tile (16 x 16B); consumed after softmax
        bf16x8 vf[16];
#pragma unroll
        for (int c8 = 0; c8 < 8; ++c8)
#pragma unroll
            for (int ksb = 0; ksb < 2; ++ksb)
                vf[c8 * 2 + ksb] = *(const bf16x8*)(vpl + c8 * 32768 + k0 + ksb * 32);

        // --- S = Q K^T (16 x 64 tile), 4 col-tiles of 16
        f32x4 s[4];
#pragma unroll
        for (int ct = 0; ct < 4; ++ct) {
            f32x4 t = z;
            t = mfma16(q0, kf[ct * 2 + 0], t);
            t = mfma16(q1, kf[ct * 2 + 1], t);
            s[ct] = t;
        }

        // --- prefetch K frags for next tile
        bf16x8 kn[8];
        if (kt != 31) {
#pragma unroll
            for (int ct = 0; ct < 4; ++ct)
#pragma unroll
                for (int ksb = 0; ksb < 2; ++ksb)
                    kn[ct * 2 + ksb] = *(const bf16x8*)(kpl + (k0 + 64) * 64 + ct * 1024 + ksb * 32);
        }

        // --- deferred-max online softmax (all values in log2 units)
        float lm[4];
        bool need = false;
#pragma unroll
        for (int i = 0; i < 4; ++i) {
            lm[i] = fmaxf(fmaxf(s[0][i], s[1][i]), fmaxf(s[2][i], s[3][i]));
            need = need || (lm[i] > m_r[i] + 8.0f);
        }
        if (__any(need)) {
#pragma unroll
            for (int i = 0; i < 4; ++i) {
                float mx = lm[i];
                mx = fmaxf(mx, __shfl_xor(mx, 1, 16));
                mx = fmaxf(mx, __shfl_xor(mx, 2, 16));
                mx = fmaxf(mx, __shfl_xor(mx, 4, 16));
                mx = fmaxf(mx, __shfl_xor(mx, 8, 16));
                float m_new = fmaxf(m_r[i], mx);
                float alpha = exp2f(m_r[i] - m_new);
#pragma unroll
                for (int c8 = 0; c8 < 8; ++c8) acc[c8][i] *= alpha;
                acc_l[i] *= alpha;
                m_r[i] = m_new;
            }
        }
        // --- P = exp2(S - m), bf16, through wave-private LDS tile
#pragma unroll
        for (int i = 0; i < 4; ++i) {
#pragma unroll
            for (int ct = 0; ct < 4; ++ct)
                p_lds[wid][lg * 4 + i][ct * 16 + lr] = f2b_hw(exp2f(s[ct][i] - m_r[i]));
        }
        bf16x8 pf0 = *(const bf16x8*)(&p_lds[wid][lr][lg * 8]);
        bf16x8 pf1 = *(const bf16x8*)(&p_lds[wid][lr][32 + lg * 8]);

        // --- PV (+ row-sum into acc_l via ones-column)
#pragma unroll
        for (int c8 = 0; c8 < 8; ++c8) {
            acc[c8] = mfma16(pf0, vf[c8 * 2 + 0], acc[c8]);
            acc[c8] = mfma16(pf1, vf[c8 * 2 + 1], acc[c8]);
        }
        acc_l = mfma16(pf0, ones, acc_l);
        acc_l = mfma16(pf1, ones, acc_l);

        if (kt != 31) {
#pragma unroll
            for (int j = 0; j < 8; ++j) kf[j] = kn[j];
        }
    }

    // --- normalize; retrieved -> LDS (fp32), rows=query, cols 0..127 = r*64+d
    float inv[4];
#pragma unroll
    for (int i = 0; i < 4; ++i) inv[i] = 1.0f / acc_l[i];
#pragma unroll
    for (int c8 = 0; c8 < 8; ++c8)
#pragma unroll
        for (int i = 0; i < 4; ++i)
            retr_lds[wid][lg * 4 + i][c8 * 16 + lr] = acc[c8][i] * inv[i];

    // --- stage 2: lane handles row = lr, d'-quarter qq = lg
    // t[d'] = sum_d wk_ret[d'][d] * rq[row][d];  sim_r = sum_d' retr[r][d']*t[d']
    // rq pre-scaled by DH^-0.5*log2e, so sims are already in exp2 units.
    const int row = lr, qq = lg;
    float t[16];
#pragma unroll
    for (int dp = 0; dp < 16; ++dp) t[dp] = 0.f;
    const unsigned short* rqrow = rqb + ((size_t)bs * 2048 + qrow0 + row) * 64;
#pragma unroll
    for (int dc = 0; dc < 8; ++dc) {
        bf16x8 rc = *(const bf16x8*)(rqrow + dc * 8);
        float rf[8];
#pragma unroll
        for (int j = 0; j < 8; ++j) rf[j] = b2f((unsigned short)rc[j]);
#pragma unroll
        for (int dp = 0; dp < 16; ++dp) {
            float acc_t = t[dp];
#pragma unroll
            for (int j = 0; j < 8; ++j)
                acc_t += wk_lds[(qq * 16 + dp) * 64 + dc * 8 + j] * rf[j];
            t[dp] = acc_t;
        }
    }
    float sim0 = 0.f, sim1 = 0.f;
#pragma unroll
    for (int dp = 0; dp < 16; ++dp) {
        sim0 += t[dp] * retr_lds[wid][row][qq * 16 + dp];
        sim1 += t[dp] * retr_lds[wid][row][64 + qq * 16 + dp];
    }
    sim0 += __shfl_xor(sim0, 16, 64); sim0 += __shfl_xor(sim0, 32, 64);
    sim1 += __shfl_xor(sim1, 16, 64); sim1 += __shfl_xor(sim1, 32, 64);
    float mm = fmaxf(sim0, sim1);
    float w0 = exp2f(sim0 - mm);
    float w1 = exp2f(sim1 - mm);
    float wsum = w0 + w1; w0 /= wsum; w1 /= wsum;

    // --- combine and write ob[b][n][gs*64 + d], 16 d per lane
    bf16x8 o0, o1;
#pragma unroll
    for (int j = 0; j < 8; ++j) {
        int d = qq * 16 + j;
        o0[j] = (short)f2b_hw(w0 * retr_lds[wid][row][d] + w1 * retr_lds[wid][row][64 + d]);
        o1[j] = (short)f2b_hw(w0 * retr_lds[wid][row][d + 8] + w1 * retr_lds[wid][row][64 + d + 8]);
    }
    unsigned short* op = ob + ((size_t)gb * 2048 + qrow0 + row) * 512 + gs * 64 + qq * 16;
    *(bf16x8*)(op) = o0;
    *(bf16x8*)(op + 8) = o1;
}

// ---------------------------------------------------------------------------
// K3: final GEMM  out[4096][512] (fp32) = ob(bf16) @ w_out, via wot = w_out^T
// grid (64, 8), 256 threads
// ---------------------------------------------------------------------------
__global__ __launch_bounds__(256) void k_out(const unsigned short* __restrict__ ob,
                                             const unsigned short* __restrict__ wot,
                                             float* __restrict__ out)
{
    const int lane = threadIdx.x & 63, wid = threadIdx.x >> 6;
    const int lr = lane & 15, lg = lane >> 4;
    const int row0 = blockIdx.x * 64 + wid * 16;
    const int col0 = blockIdx.y * 64;

    const f32x4 z = {0.f, 0.f, 0.f, 0.f};
    f32x4 acc[4];
#pragma unroll
    for (int ct = 0; ct < 4; ++ct) acc[ct] = z;

    const unsigned short* ap = ob + (row0 + lr) * 512 + lg * 8;
#pragma unroll 4
    for (int k0 = 0; k0 < 512; k0 += 32) {
        bf16x8 a = *(const bf16x8*)(ap + k0);
#pragma unroll
        for (int ct = 0; ct < 4; ++ct) {
            bf16x8 b = *(const bf16x8*)(wot + (col0 + ct * 16 + lr) * 512 + k0 + lg * 8);
            acc[ct] = mfma16(a, b, acc[ct]);
        }
    }
#pragma unroll
    for (int ct = 0; ct < 4; ++ct)
#pragma unroll
        for (int i = 0; i < 4; ++i)
            out[(size_t)(row0 + lg * 4 + i) * 512 + col0 + ct * 16 + lr] = acc[ct][i];
}

// ---------------------------------------------------------------------------
extern "C" void kernel_launch(void* const* d_in, const int* in_sizes, int n_in,
                              void* d_out, int out_size, void* d_ws, size_t ws_size,
                              hipStream_t stream)
{
    (void)in_sizes; (void)n_in; (void)out_size; (void)ws_size;
    const float* x      = (const float*)d_in[0];
    const float* wq_s   = (const float*)d_in[1];
    const float* wk_s   = (const float*)d_in[2];
    const float* wv_r   = (const float*)d_in[3];
    const float* wq_r   = (const float*)d_in[4];
    const float* wk_ret = (const float*)d_in[5];
    const float* w_out  = (const float*)d_in[6];

    char* ws = (char*)d_ws;                            // needs ~24.3 MB
    unsigned short* xb  = (unsigned short*)(ws + 0);          // [4096][512]
    unsigned short* wt  = (unsigned short*)(ws + 4194304);    // [1664][512]
    unsigned short* qsb = (unsigned short*)(ws + 5898240);    // [2][8][2048][64]
    unsigned short* ksb = (unsigned short*)(ws + 10092544);   // [2][8][2048][64]
    unsigned short* rqb = (unsigned short*)(ws + 14286848);   // [2][8][2048][64]
    unsigned short* vtb = (unsigned short*)(ws + 18481152);   // [2][128][2048]
    unsigned short* obb = (unsigned short*)(ws + 19529728);   // [2][2048][512]
    unsigned short* wot = (unsigned short*)(ws + 23724032);   // [512][512]

    hipLaunchKernelGGL(k_convert, dim3(2048), dim3(256), 0, stream,
                       x, wq_s, wk_s, wv_r, wq_r, w_out, xb, wt, wot);
    hipLaunchKernelGGL(k_proj, dim3(64, 26), dim3(256), 0, stream,
                       xb, wt, qsb, ksb, rqb, vtb);
    hipLaunchKernelGGL(k_attn, dim3(512), dim3(256), 0, stream,
                       qsb, ksb, rqb, vtb, wk_ret, obb);
    hipLaunchKernelGGL(k_out, dim3(64, 8), dim3(256), 0, stream,
                       obb, wot, (float*)d_out);
}